// Round 2
// baseline (6572.440 us; speedup 1.0000x reference)
//
#include <hip/hip_runtime.h>
#include <math.h>

#define BATCH 16
#define CIN   128
#define HH    192
#define WW    192
#define HW    (HH*WW)
#define OC    64
#define KPTS  512

// ---------------- K1: global mean pool over H,W (f64) ----------------
__global__ __launch_bounds__(256) void pool_kernel(const float* __restrict__ feat,
                                                   double* __restrict__ pool) {
  int bc = blockIdx.x;  // 0..2047
  const float4* fp = (const float4*)(feat + (size_t)bc * HW);
  double s = 0.0;
  for (int i = threadIdx.x; i < HW/4; i += 256) {
    float4 v = fp[i];
    s += (double)v.x + (double)v.y + (double)v.z + (double)v.w;
  }
  for (int off = 32; off > 0; off >>= 1) s += __shfl_down(s, off, 64);
  __shared__ double sb[4];
  int lane = threadIdx.x & 63, wv = threadIdx.x >> 6;
  if (lane == 0) sb[wv] = s;
  __syncthreads();
  if (threadIdx.x == 0) {
    double t = sb[0] + sb[1] + sb[2] + sb[3];
    pool[bc] = t / 36864.0;
  }
}

// ---------------- K2: attn = sigmoid(pool @ attn_w.T + attn_b) (f64) ----------------
__global__ __launch_bounds__(128) void attn_kernel(const double* __restrict__ pool,
                                                   const float* __restrict__ attn_w,
                                                   const float* __restrict__ attn_b,
                                                   double* __restrict__ attn) {
  __shared__ double sp[CIN];
  int b = blockIdx.x, c = threadIdx.x;
  sp[c] = pool[b*CIN + c];
  __syncthreads();
  double s = (double)attn_b[c];
  const float* wr = attn_w + (size_t)c * CIN;
  for (int j = 0; j < CIN; j++) s = fma((double)wr[j], sp[j], s);
  attn[b*CIN + c] = 1.0 / (1.0 + exp(-s));
}

// ---------------- K2b: conv1_w [64][128][9] -> wTd [128][9][64] (f64) ----------------
__global__ __launch_bounds__(256) void wtrans_kernel(const float* __restrict__ w,
                                                     double* __restrict__ wTd) {
  int i = blockIdx.x * 256 + threadIdx.x;
  if (i < OC*CIN*9) {
    int oc = i / (CIN*9);
    int r  = i % (CIN*9);
    int c  = r / 9;
    int k  = r % 9;
    wTd[(c*9 + k)*OC + oc] = (double)w[i];
  }
}

// ---------------- K3: fused conv3x3(128->64) + GeLU + conv1x1(64->2), f64 acc ----------------
#define CC 16
__global__ __launch_bounds__(256) void conv_kernel(const float* __restrict__ feat,
                                                   const double* __restrict__ attn,
                                                   const double* __restrict__ wTd,
                                                   const float* __restrict__ conv1_b,
                                                   const float* __restrict__ conv2_w,
                                                   const float* __restrict__ conv2_b,
                                                   float* __restrict__ depth_out,
                                                   double* __restrict__ logit_d) {
  __shared__ float tile[CC][18*18];
  __shared__ double s_attn[CIN];
  const int b  = blockIdx.z;
  const int h0 = blockIdx.y * 16, w0 = blockIdx.x * 16;
  const int tid = threadIdx.x;
  const int tx = tid & 15, ty = tid >> 4;

  if (tid < CIN) s_attn[tid] = attn[b*CIN + tid];
  __syncthreads();

  double acc[OC];
  #pragma unroll
  for (int i = 0; i < OC; i++) acc[i] = 0.0;

  for (int c0 = 0; c0 < CIN; c0 += CC) {
    // stage RAW input tile (fp32, zero padded); attn applied at read (f64, matches np x=feat64*attn64)
    for (int i = tid; i < CC*324; i += 256) {
      int cc = i / 324;
      int r  = i % 324;
      int rh = r / 18, rw = r % 18;
      int gh = h0 + rh - 1, gw = w0 + rw - 1;
      float v = 0.f;
      if (gh >= 0 && gh < HH && gw >= 0 && gw < WW)
        v = feat[((size_t)(b*CIN + c0 + cc)*HH + gh)*WW + gw];
      tile[cc][r] = v;
    }
    __syncthreads();
    for (int cc = 0; cc < CC; cc++) {
      double a = s_attn[c0 + cc];
      double xv[9];
      #pragma unroll
      for (int dy = 0; dy < 3; dy++)
        #pragma unroll
        for (int dx = 0; dx < 3; dx++)
          xv[dy*3+dx] = (double)tile[cc][(ty+dy)*18 + tx + dx] * a;
      const double* wp = wTd + (size_t)(c0 + cc) * 9 * OC;  // block-uniform -> s_load
      #pragma unroll
      for (int k = 0; k < 9; k++) {
        double xk = xv[k];
        #pragma unroll
        for (int oc = 0; oc < OC; oc++)
          acc[oc] = fma(wp[k*OC + oc], xk, acc[oc]);
      }
    }
    __syncthreads();
  }

  double o0 = 0.0, o1 = 0.0;
  #pragma unroll
  for (int oc = 0; oc < OC; oc++) {
    double z = acc[oc] + (double)conv1_b[oc];
    double g = 0.5 * z * (1.0 + erf(z * 0.70710678118654752440));  // exact gelu
    o0 = fma((double)conv2_w[oc],      g, o0);
    o1 = fma((double)conv2_w[OC + oc], g, o1);
  }
  o0 += (double)conv2_b[0];
  o1 += (double)conv2_b[1];
  const int h = h0 + ty, w = w0 + tx;
  depth_out[((size_t)b*HH + h)*WW + w] = (float)o0;
  logit_d[((size_t)b*HH + h)*WW + w] = o1;
}

// ---------------- K4: per-batch softmax over HW (f64, in-place safe) ----------------
__global__ __launch_bounds__(1024) void softmax_kernel(const double* __restrict__ logits,
                                                       double* __restrict__ probs) {
  const int b = blockIdx.x;
  const double* lp = logits + (size_t)b * HW;
  double* pp = probs + (size_t)b * HW;
  const int tid = threadIdx.x;
  __shared__ double sred[16];
  __shared__ double s_m, s_z;

  double m = -INFINITY;
  for (int i = tid; i < HW; i += 1024) m = fmax(m, lp[i]);
  for (int off = 32; off > 0; off >>= 1) m = fmax(m, __shfl_down(m, off, 64));
  if ((tid & 63) == 0) sred[tid >> 6] = m;
  __syncthreads();
  if (tid == 0) {
    double t = sred[0];
    for (int i = 1; i < 16; i++) t = fmax(t, sred[i]);
    s_m = t;
  }
  __syncthreads();
  m = s_m;

  double z = 0.0;
  for (int i = tid; i < HW; i += 1024) z += exp(lp[i] - m);
  __syncthreads();
  for (int off = 32; off > 0; off >>= 1) z += __shfl_down(z, off, 64);
  if ((tid & 63) == 0) sred[tid >> 6] = z;
  __syncthreads();
  if (tid == 0) {
    double t = 0.0;
    for (int i = 0; i < 16; i++) t += sred[i];
    s_z = t;
  }
  __syncthreads();
  z = s_z;

  for (int i = tid; i < HW; i += 1024) pp[i] = exp(lp[i] - m) / z;
}

// ---------------- K5: 3x3 box filter (zero pad) / 9 (f64) + fp32 out ----------------
__global__ __launch_bounds__(256) void box_kernel(const double* __restrict__ p,
                                                  double* __restrict__ out_d,
                                                  float* __restrict__ out_f) {
  int i = blockIdx.x * 256 + threadIdx.x;
  if (i >= BATCH * HW) return;
  int b = i / HW, r = i % HW, h = r / WW, w = r % WW;
  const double* bp = p + (size_t)b * HW;
  double s = 0.0;
  for (int dy = -1; dy <= 1; dy++) {
    int h2 = h + dy;
    if (h2 < 0 || h2 >= HH) continue;
    for (int dx = -1; dx <= 1; dx++) {
      int w2 = w + dx;
      if (w2 < 0 || w2 >= WW) continue;
      s += bp[h2*WW + w2];
    }
  }
  double c = s / 9.0;
  out_d[i] = c;
  out_f[i] = (float)c;
}

// ---------------- K6: per-batch exact top-512 on f64 conf (desc value, asc index) ----------------
__global__ __launch_bounds__(1024) void topk_kernel(const double* __restrict__ conf,
                                                    const float* __restrict__ depth,
                                                    float* __restrict__ points) {
  const int b = blockIdx.x;
  const double* cp = conf + (size_t)b * HW;
  const int tid = threadIdx.x;
  __shared__ unsigned sred[16];
  __shared__ unsigned s_total;
  __shared__ unsigned s_cnt;
  __shared__ double vals[1024];
  __shared__ int    idxs[1024];

  // binary search for the 512th-largest value's bit pattern (conf > 0 always)
  unsigned long long lo = 0ull, hi = 0x3FF0000000000000ull;  // [0, 1.0)
  while (hi - lo > 1ull) {
    unsigned long long mid = lo + ((hi - lo) >> 1);
    unsigned cnt = 0;
    for (int i = tid; i < HW; i += 1024)
      cnt += ((unsigned long long)__double_as_longlong(cp[i]) >= mid) ? 1u : 0u;
    for (int off = 32; off > 0; off >>= 1) cnt += __shfl_down(cnt, off, 64);
    if ((tid & 63) == 0) sred[tid >> 6] = cnt;
    __syncthreads();
    if (tid == 0) {
      unsigned t = 0;
      for (int i = 0; i < 16; i++) t += sred[i];
      s_total = t;
    }
    __syncthreads();
    unsigned total = s_total;
    __syncthreads();
    if (total >= KPTS) lo = mid; else hi = mid;
  }

  if (tid == 0) s_cnt = 0;
  __syncthreads();
  for (int i = tid; i < HW; i += 1024) {
    unsigned long long bits = (unsigned long long)__double_as_longlong(cp[i]);
    if (bits >= lo) {
      unsigned slot = atomicAdd(&s_cnt, 1u);
      if (slot < 1024u) { vals[slot] = cp[i]; idxs[slot] = i; }
    }
  }
  __syncthreads();
  unsigned n = s_cnt; if (n > 1024u) n = 1024u;
  if ((unsigned)tid >= n) { vals[tid] = -1.0; idxs[tid] = 0x7FFFFFFF; }
  __syncthreads();

  // bitonic sort: descending by val, ascending by idx on ties
  for (unsigned k = 2; k <= 1024; k <<= 1) {
    for (unsigned j = k >> 1; j > 0; j >>= 1) {
      unsigned i = (unsigned)tid;
      unsigned ixj = i ^ j;
      if (ixj > i) {
        double va = vals[i], vc = vals[ixj];
        int    ia = idxs[i], ic = idxs[ixj];
        // "a ranks after c" in descending order:
        bool aAfterC = (va < vc) || (va == vc && ia > ic);
        bool descSeg = ((i & k) == 0);
        bool doSwap = descSeg ? aAfterC : !aAfterC;
        if (doSwap) { vals[i] = vc; idxs[i] = ia == ia ? ic : ic; idxs[i] = ic;
                      vals[ixj] = va; idxs[ixj] = ia; }
      }
      __syncthreads();
    }
  }

  if (tid < KPTS) {
    int idx = idxs[tid];
    float d = depth[(size_t)b * HW + idx];
    float xi = (float)(idx % WW) / (float)WW;
    float yi = (float)(idx / WW) / (float)HH;
    float* pp = points + ((size_t)b * KPTS + tid) * 3;
    pp[0] = xi; pp[1] = yi; pp[2] = d;
  }
}

extern "C" void kernel_launch(void* const* d_in, const int* in_sizes, int n_in,
                              void* d_out, int out_size, void* d_ws, size_t ws_size,
                              hipStream_t stream) {
  const float* feat    = (const float*)d_in[0];
  const float* attn_w  = (const float*)d_in[1];
  const float* attn_b  = (const float*)d_in[2];
  const float* conv1_w = (const float*)d_in[3];
  const float* conv1_b = (const float*)d_in[4];
  const float* conv2_w = (const float*)d_in[5];
  const float* conv2_b = (const float*)d_in[6];

  float* out    = (float*)d_out;
  float* points = out;                          // 16*512*3 = 24576
  float* depth  = out + 24576;                  // 16*36864
  float* conf_f = out + 24576 + BATCH*HW;       // 16*36864

  double* wsd     = (double*)d_ws;
  double* pool_d  = wsd;                        // 2048
  double* attn_d  = wsd + 2048;                 // 2048
  double* wTd     = wsd + 4096;                 // 73728
  double* logit_d = wsd + 4096 + 73728;         // 589824 (also reused as probs, in place)
  double* conf_d  = logit_d + (size_t)BATCH*HW; // 589824   (total ~10.1 MB)

  pool_kernel<<<BATCH*CIN, 256, 0, stream>>>(feat, pool_d);
  attn_kernel<<<BATCH, CIN, 0, stream>>>(pool_d, attn_w, attn_b, attn_d);
  wtrans_kernel<<<(OC*CIN*9 + 255)/256, 256, 0, stream>>>(conv1_w, wTd);
  dim3 cgrid(WW/16, HH/16, BATCH);
  conv_kernel<<<cgrid, 256, 0, stream>>>(feat, attn_d, wTd, conv1_b, conv2_w, conv2_b,
                                         depth, logit_d);
  softmax_kernel<<<BATCH, 1024, 0, stream>>>(logit_d, logit_d);  // in-place safe
  box_kernel<<<(BATCH*HW + 255)/256, 256, 0, stream>>>(logit_d, conf_d, conf_f);
  topk_kernel<<<BATCH, 1024, 0, stream>>>(conf_d, depth, points);
}

// Round 3
// 2674.269 us; speedup vs baseline: 2.4577x; 2.4577x over previous
//
#include <hip/hip_runtime.h>
#include <math.h>

#define BATCH 16
#define CIN   128
#define HH    192
#define WW    192
#define HW    (HH*WW)
#define OC    64
#define KPTS  512
#define CAP   1024

// ---------------- K1: global mean pool over H,W (f64 acc) ----------------
__global__ __launch_bounds__(256) void pool_kernel(const float* __restrict__ feat,
                                                   double* __restrict__ pool) {
  int bc = blockIdx.x;  // 0..2047
  const float4* fp = (const float4*)(feat + (size_t)bc * HW);
  double s = 0.0;
  for (int i = threadIdx.x; i < HW/4; i += 256) {
    float4 v = fp[i];
    s += (double)v.x + (double)v.y + (double)v.z + (double)v.w;
  }
  for (int off = 32; off > 0; off >>= 1) s += __shfl_down(s, off, 64);
  __shared__ double sb[4];
  int lane = threadIdx.x & 63, wv = threadIdx.x >> 6;
  if (lane == 0) sb[wv] = s;
  __syncthreads();
  if (threadIdx.x == 0) {
    double t = sb[0] + sb[1] + sb[2] + sb[3];
    pool[bc] = t / 36864.0;
  }
}

// ---------------- K2: attn = sigmoid(pool @ attn_w.T + attn_b) (f64 + f32 copy) ----------------
__global__ __launch_bounds__(128) void attn_kernel(const double* __restrict__ pool,
                                                   const float* __restrict__ attn_w,
                                                   const float* __restrict__ attn_b,
                                                   double* __restrict__ attn_d,
                                                   float* __restrict__ attn_f) {
  __shared__ double sp[CIN];
  int b = blockIdx.x, c = threadIdx.x;
  sp[c] = pool[b*CIN + c];
  __syncthreads();
  double s = (double)attn_b[c];
  const float* wr = attn_w + (size_t)c * CIN;
  for (int j = 0; j < CIN; j++) s = fma((double)wr[j], sp[j], s);
  double a = 1.0 / (1.0 + exp(-s));
  attn_d[b*CIN + c] = a;
  attn_f[b*CIN + c] = (float)a;
}

// ---------------- K2b: weights: wT32 [c][k][oc] f32, wd64 = f64 copy of conv1_w ----------------
__global__ __launch_bounds__(256) void wtrans_kernel(const float* __restrict__ w,
                                                     float* __restrict__ wT32,
                                                     double* __restrict__ wd64) {
  int i = blockIdx.x * 256 + threadIdx.x;
  if (i < OC*CIN*9) {
    int oc = i / (CIN*9);
    int r  = i % (CIN*9);
    int c  = r / 9;
    int k  = r % 9;
    wT32[(c*9 + k)*OC + oc] = w[i];
    wd64[i] = (double)w[i];
  }
}

// ---------------- K3: fused conv3x3(128->64) + GeLU + conv1x1(64->2), fp32 ----------------
#define CC 16
__global__ __launch_bounds__(256) void conv_kernel(const float* __restrict__ feat,
                                                   const float* __restrict__ attn,
                                                   const float* __restrict__ wT,
                                                   const float* __restrict__ conv1_b,
                                                   const float* __restrict__ conv2_w,
                                                   const float* __restrict__ conv2_b,
                                                   float* __restrict__ depth_out,
                                                   float* __restrict__ logit_out) {
  __shared__ float tile[CC][18*18];
  __shared__ float s_attn[CIN];
  const int b  = blockIdx.z;
  const int h0 = blockIdx.y * 16, w0 = blockIdx.x * 16;
  const int tid = threadIdx.x;
  const int tx = tid & 15, ty = tid >> 4;

  if (tid < CIN) s_attn[tid] = attn[b*CIN + tid];
  __syncthreads();

  float acc[OC];
  #pragma unroll
  for (int i = 0; i < OC; i++) acc[i] = 0.f;

  for (int c0 = 0; c0 < CIN; c0 += CC) {
    for (int i = tid; i < CC*324; i += 256) {
      int cc = i / 324;
      int r  = i % 324;
      int rh = r / 18, rw = r % 18;
      int gh = h0 + rh - 1, gw = w0 + rw - 1;
      float v = 0.f;
      if (gh >= 0 && gh < HH && gw >= 0 && gw < WW)
        v = feat[((size_t)(b*CIN + c0 + cc)*HH + gh)*WW + gw] * s_attn[c0 + cc];
      tile[cc][r] = v;
    }
    __syncthreads();
    for (int cc = 0; cc < CC; cc++) {
      float xv[9];
      #pragma unroll
      for (int dy = 0; dy < 3; dy++)
        #pragma unroll
        for (int dx = 0; dx < 3; dx++)
          xv[dy*3+dx] = tile[cc][(ty+dy)*18 + tx + dx];
      const float* wp = wT + (size_t)(c0 + cc) * 9 * OC;  // block-uniform -> s_load
      #pragma unroll
      for (int k = 0; k < 9; k++) {
        float xk = xv[k];
        #pragma unroll
        for (int oc = 0; oc < OC; oc++)
          acc[oc] = fmaf(wp[k*OC + oc], xk, acc[oc]);
      }
    }
    __syncthreads();
  }

  float o0 = 0.f, o1 = 0.f;
  #pragma unroll
  for (int oc = 0; oc < OC; oc++) {
    float z = acc[oc] + conv1_b[oc];
    float g = 0.5f * z * (1.0f + erff(z * 0.70710678118654752f));
    o0 = fmaf(conv2_w[oc],      g, o0);
    o1 = fmaf(conv2_w[OC + oc], g, o1);
  }
  o0 += conv2_b[0];
  o1 += conv2_b[1];
  const int h = h0 + ty, w = w0 + tx;
  depth_out[((size_t)b*HH + h)*WW + w] = o0;
  logit_out[((size_t)b*HH + h)*WW + w] = o1;
}

// ---------------- K4: per-batch softmax over HW (fp32, in place) + save max ----------------
__global__ __launch_bounds__(1024) void softmax_kernel(float* __restrict__ logits,
                                                       float* __restrict__ m_out) {
  const int b = blockIdx.x;
  float* lp = logits + (size_t)b * HW;
  const int tid = threadIdx.x;
  __shared__ float sred[16];
  __shared__ float s_m, s_z;

  float m = -INFINITY;
  for (int i = tid; i < HW; i += 1024) m = fmaxf(m, lp[i]);
  for (int off = 32; off > 0; off >>= 1) m = fmaxf(m, __shfl_down(m, off, 64));
  if ((tid & 63) == 0) sred[tid >> 6] = m;
  __syncthreads();
  if (tid == 0) {
    float t = sred[0];
    for (int i = 1; i < 16; i++) t = fmaxf(t, sred[i]);
    s_m = t;
    m_out[b] = t;
  }
  __syncthreads();
  m = s_m;

  float z = 0.f;
  for (int i = tid; i < HW; i += 1024) z += expf(lp[i] - m);
  __syncthreads();
  for (int off = 32; off > 0; off >>= 1) z += __shfl_down(z, off, 64);
  if ((tid & 63) == 0) sred[tid >> 6] = z;
  __syncthreads();
  if (tid == 0) {
    float t = 0.f;
    for (int i = 0; i < 16; i++) t += sred[i];
    s_z = t;
  }
  __syncthreads();
  z = s_z;

  for (int i = tid; i < HW; i += 1024) lp[i] = expf(lp[i] - m) / z;
}

// ---------------- K5: 3x3 box filter (zero pad) / 9, fp32 ----------------
__global__ __launch_bounds__(256) void box_kernel(const float* __restrict__ p,
                                                  float* __restrict__ out_f) {
  int i = blockIdx.x * 256 + threadIdx.x;
  if (i >= BATCH * HW) return;
  int b = i / HW, r = i % HW, h = r / WW, w = r % WW;
  const float* bp = p + (size_t)b * HW;
  float s = 0.f;
  for (int dy = -1; dy <= 1; dy++) {
    int h2 = h + dy;
    if (h2 < 0 || h2 >= HH) continue;
    for (int dx = -1; dx <= 1; dx++) {
      int w2 = w + dx;
      if (w2 < 0 || w2 >= WW) continue;
      s += bp[h2*WW + w2];
    }
  }
  out_f[i] = s / 9.0f;
}

// ---------------- K6: per-batch candidate selection (conf32 >= cut512*(1-1e-3)) ----------------
__global__ __launch_bounds__(1024) void cand_kernel(const float* __restrict__ conf,
                                                    int* __restrict__ cand_idx,
                                                    int* __restrict__ cand_cnt) {
  const int b = blockIdx.x;
  const float* cp = conf + (size_t)b * HW;
  const int tid = threadIdx.x;
  __shared__ unsigned sred[16];
  __shared__ unsigned s_total;
  __shared__ unsigned s_cnt;

  unsigned lo = 0u, hi = 0x7F800000u;   // conf > 0 always
  while (hi - lo > 1u) {
    unsigned mid = lo + ((hi - lo) >> 1);
    unsigned cnt = 0;
    for (int i = tid; i < HW; i += 1024)
      cnt += (__float_as_uint(cp[i]) >= mid) ? 1u : 0u;
    for (int off = 32; off > 0; off >>= 1) cnt += __shfl_down(cnt, off, 64);
    if ((tid & 63) == 0) sred[tid >> 6] = cnt;
    __syncthreads();
    if (tid == 0) {
      unsigned t = 0;
      for (int i = 0; i < 16; i++) t += sred[i];
      s_total = t;
    }
    __syncthreads();
    unsigned total = s_total;
    __syncthreads();
    if (total >= KPTS) lo = mid; else hi = mid;
  }
  float vcut = __uint_as_float(lo) * (1.0f - 1e-3f);

  if (tid == 0) s_cnt = 0;
  __syncthreads();
  for (int i = tid; i < HW; i += 1024) {
    if (cp[i] >= vcut) {
      unsigned s = atomicAdd(&s_cnt, 1u);
      if (s < CAP) cand_idx[b*CAP + s] = i;
    }
  }
  __syncthreads();
  if (tid == 0) cand_cnt[b] = (s_cnt < CAP) ? s_cnt : CAP;
}

// ---------------- K7: f64 refinement — score = sum_j exp64(l64_j - m32) ----------------
__global__ __launch_bounds__(256) void refine_kernel(const float* __restrict__ feat,
                                                     const double* __restrict__ attn_d,
                                                     const double* __restrict__ wd64,
                                                     const float* __restrict__ conv1_b,
                                                     const float* __restrict__ conv2_w,
                                                     const float* __restrict__ conv2_b,
                                                     const float* __restrict__ m32,
                                                     const int* __restrict__ cand_idx,
                                                     const int* __restrict__ cand_cnt,
                                                     double* __restrict__ cand_score) {
  const int b = blockIdx.y, slot = blockIdx.x;
  if (slot >= cand_cnt[b]) return;
  const int idx = cand_idx[b*CAP + slot];
  const int ph = idx / WW, pw = idx % WW;
  const int tid = threadIdx.x;

  __shared__ double xwin[CIN][25];   // 25.6 KB, x64 = feat64 * attn64 on 5x5 window
  __shared__ double part[4][9][64];  // 18.4 KB
  __shared__ double cont[9][64];     // 4.6 KB
  __shared__ double lval[9];

  for (int i = tid; i < CIN*25; i += 256) {
    int c = i / 25, rr = i % 25;
    int r = rr / 5, s = rr % 5;
    int gh = ph + r - 2, gw = pw + s - 2;
    float v = 0.f;
    if (gh >= 0 && gh < HH && gw >= 0 && gw < WW)
      v = feat[((size_t)(b*CIN + c)*HH + gh)*WW + gw];
    xwin[c][rr] = (double)v * attn_d[b*CIN + c];
  }
  __syncthreads();

  const int oc = tid & 63, cq = tid >> 6;   // wave: same cq, oc 0..63 -> LDS broadcast
  double acc9[9];
  #pragma unroll
  for (int j = 0; j < 9; j++) acc9[j] = 0.0;
  const double* wp = wd64 + ((size_t)oc*CIN + cq*32) * 9;

  for (int ci = 0; ci < 32; ci++) {
    int c = cq*32 + ci;
    double xv[25];
    #pragma unroll
    for (int r = 0; r < 25; r++) xv[r] = xwin[c][r];
    #pragma unroll
    for (int k = 0; k < 9; k++) {
      double w = wp[ci*9 + k];
      const int u = k/3, v = k%3;
      #pragma unroll
      for (int j = 0; j < 9; j++) {
        const int a = j/3, bb = j%3;
        acc9[j] = fma(w, xv[(a+u)*5 + (bb+v)], acc9[j]);
      }
    }
  }
  #pragma unroll
  for (int j = 0; j < 9; j++) part[cq][j][oc] = acc9[j];
  __syncthreads();

  for (int t = tid; t < 576; t += 256) {
    int j = t >> 6, o = t & 63;
    double z = part[0][j][o] + part[1][j][o] + part[2][j][o] + part[3][j][o]
             + (double)conv1_b[o];
    double g = 0.5 * z * (1.0 + erf(z * 0.70710678118654752440));
    cont[j][o] = g * (double)conv2_w[OC + o];
  }
  __syncthreads();
  if (tid < 9) {
    double s = 0.0;
    for (int o = 0; o < 64; o++) s += cont[tid][o];
    lval[tid] = s + (double)conv2_b[1];
  }
  __syncthreads();
  if (tid == 0) {
    double m = (double)m32[b];
    double sc = 0.0;
    #pragma unroll
    for (int j = 0; j < 9; j++) {
      int a = j/3 - 1, bb = j%3 - 1;
      int qh = ph + a, qw = pw + bb;
      if (qh >= 0 && qh < HH && qw >= 0 && qw < WW)
        sc += exp(lval[j] - m);
    }
    cand_score[b*CAP + slot] = sc;
  }
}

// ---------------- K8: per-batch sort candidates (score desc, idx asc) + emit points ----------------
__global__ __launch_bounds__(1024) void emit_kernel(const double* __restrict__ cand_score,
                                                    const int* __restrict__ cand_idx,
                                                    const int* __restrict__ cand_cnt,
                                                    const float* __restrict__ depth,
                                                    float* __restrict__ points) {
  const int b = blockIdx.x;
  const int tid = threadIdx.x;
  __shared__ double vals[CAP];
  __shared__ int    idxs[CAP];

  int cnt = cand_cnt[b];
  if (tid < cnt) { vals[tid] = cand_score[b*CAP + tid]; idxs[tid] = cand_idx[b*CAP + tid]; }
  else           { vals[tid] = -1.0;                    idxs[tid] = 0x7FFFFFFF; }
  __syncthreads();

  for (unsigned k = 2; k <= CAP; k <<= 1) {
    for (unsigned j = k >> 1; j > 0; j >>= 1) {
      unsigned i = (unsigned)tid;
      unsigned ixj = i ^ j;
      if (ixj > i) {
        double va = vals[i], vc = vals[ixj];
        int    ia = idxs[i], ic = idxs[ixj];
        bool aAfterC = (va < vc) || (va == vc && ia > ic);
        bool descSeg = ((i & k) == 0);
        bool doSwap = descSeg ? aAfterC : !aAfterC;
        if (doSwap) { vals[i] = vc; idxs[i] = ic; vals[ixj] = va; idxs[ixj] = ia; }
      }
      __syncthreads();
    }
  }

  if (tid < KPTS) {
    int idx = idxs[tid];
    float d = depth[(size_t)b * HW + idx];
    float xi = (float)(idx % WW) / (float)WW;
    float yi = (float)(idx / WW) / (float)HH;
    float* pp = points + ((size_t)b * KPTS + tid) * 3;
    pp[0] = xi; pp[1] = yi; pp[2] = d;
  }
}

extern "C" void kernel_launch(void* const* d_in, const int* in_sizes, int n_in,
                              void* d_out, int out_size, void* d_ws, size_t ws_size,
                              hipStream_t stream) {
  const float* feat    = (const float*)d_in[0];
  const float* attn_w  = (const float*)d_in[1];
  const float* attn_b  = (const float*)d_in[2];
  const float* conv1_w = (const float*)d_in[3];
  const float* conv1_b = (const float*)d_in[4];
  const float* conv2_w = (const float*)d_in[5];
  const float* conv2_b = (const float*)d_in[6];

  float* out    = (float*)d_out;
  float* points = out;                          // 16*512*3
  float* depth  = out + 24576;                  // 16*36864
  float* conf_f = out + 24576 + BATCH*HW;       // 16*36864

  // ws layout: doubles first (alignment), then floats, then ints
  double* wsd        = (double*)d_ws;
  double* pool_d     = wsd;                                    // 2048
  double* attn_d     = wsd + 2048;                             // 2048
  double* wd64       = wsd + 4096;                             // 73728
  double* cand_score = wsd + 4096 + 73728;                     // 16*1024
  float*  wsf        = (float*)(cand_score + BATCH*CAP);
  float*  wT32       = wsf;                                    // 73728
  float*  logit32    = wsf + 73728;                            // 589824 (reused as probs)
  float*  attn_f     = logit32 + (size_t)BATCH*HW;             // 2048
  float*  m32        = attn_f + 2048;                          // 16
  int*    cand_idx   = (int*)(m32 + 16);                       // 16*1024
  int*    cand_cnt   = cand_idx + BATCH*CAP;                   // 16

  pool_kernel<<<BATCH*CIN, 256, 0, stream>>>(feat, pool_d);
  attn_kernel<<<BATCH, CIN, 0, stream>>>(pool_d, attn_w, attn_b, attn_d, attn_f);
  wtrans_kernel<<<(OC*CIN*9 + 255)/256, 256, 0, stream>>>(conv1_w, wT32, wd64);
  dim3 cgrid(WW/16, HH/16, BATCH);
  conv_kernel<<<cgrid, 256, 0, stream>>>(feat, attn_f, wT32, conv1_b, conv2_w, conv2_b,
                                         depth, logit32);
  softmax_kernel<<<BATCH, 1024, 0, stream>>>(logit32, m32);   // in-place probs
  box_kernel<<<(BATCH*HW + 255)/256, 256, 0, stream>>>(logit32, conf_f);
  cand_kernel<<<BATCH, 1024, 0, stream>>>(conf_f, cand_idx, cand_cnt);
  refine_kernel<<<dim3(CAP, BATCH), 256, 0, stream>>>(feat, attn_d, wd64, conv1_b,
                                                      conv2_w, conv2_b, m32,
                                                      cand_idx, cand_cnt, cand_score);
  emit_kernel<<<BATCH, 1024, 0, stream>>>(cand_score, cand_idx, cand_cnt, depth, points);
}

// Round 4
// 2305.174 us; speedup vs baseline: 2.8512x; 1.1601x over previous
//
#include <hip/hip_runtime.h>
#include <math.h>

#define BATCH 16
#define CIN   128
#define HH    192
#define WW    192
#define HW    (HH*WW)
#define OC    64
#define KPTS  512
#define CAP   2048

typedef short short8 __attribute__((ext_vector_type(8)));
typedef float f32x4 __attribute__((ext_vector_type(4)));

__device__ __forceinline__ unsigned short rne_bf16(float v) {
  unsigned u = __float_as_uint(v);
  u += 0x7FFFu + ((u >> 16) & 1u);
  return (unsigned short)(u >> 16);
}

// ---------------- K1: global mean pool over H,W (f64 acc) ----------------
__global__ __launch_bounds__(256) void pool_kernel(const float* __restrict__ feat,
                                                   double* __restrict__ pool) {
  int bc = blockIdx.x;  // 0..2047
  const float4* fp = (const float4*)(feat + (size_t)bc * HW);
  double s = 0.0;
  for (int i = threadIdx.x; i < HW/4; i += 256) {
    float4 v = fp[i];
    s += (double)v.x + (double)v.y + (double)v.z + (double)v.w;
  }
  for (int off = 32; off > 0; off >>= 1) s += __shfl_down(s, off, 64);
  __shared__ double sb[4];
  int lane = threadIdx.x & 63, wv = threadIdx.x >> 6;
  if (lane == 0) sb[wv] = s;
  __syncthreads();
  if (threadIdx.x == 0) {
    double t = sb[0] + sb[1] + sb[2] + sb[3];
    pool[bc] = t / 36864.0;
  }
}

// ---------------- K2: attn = sigmoid(pool @ attn_w.T + attn_b) (f64 + f32 copy) ----------------
__global__ __launch_bounds__(128) void attn_kernel(const double* __restrict__ pool,
                                                   const float* __restrict__ attn_w,
                                                   const float* __restrict__ attn_b,
                                                   double* __restrict__ attn_d,
                                                   float* __restrict__ attn_f) {
  __shared__ double sp[CIN];
  int b = blockIdx.x, c = threadIdx.x;
  sp[c] = pool[b*CIN + c];
  __syncthreads();
  double s = (double)attn_b[c];
  const float* wr = attn_w + (size_t)c * CIN;
  for (int j = 0; j < CIN; j++) s = fma((double)wr[j], sp[j], s);
  double a = 1.0 / (1.0 + exp(-s));
  attn_d[b*CIN + c] = a;
  attn_f[b*CIN + c] = (float)a;
}

// ---------------- K2b: weights: wbf [tap][oc][c] bf16, wd64 = f64 copy ----------------
__global__ __launch_bounds__(256) void wtrans_kernel(const float* __restrict__ w,
                                                     unsigned short* __restrict__ wbf,
                                                     double* __restrict__ wd64) {
  int i = blockIdx.x * 256 + threadIdx.x;
  if (i < OC*CIN*9) {
    int oc = i / (CIN*9);
    int r  = i % (CIN*9);
    int c  = r / 9;
    int k  = r % 9;
    float v = w[i];
    wd64[i] = (double)v;
    wbf[((size_t)k*OC + oc)*CIN + c] = rne_bf16(v);
  }
}

// ---------------- K3: MFMA conv3x3(128->64) + GeLU + conv1x1(64->2) ----------------
#define PADC 40
__global__ __launch_bounds__(256) void conv_kernel(const float* __restrict__ feat,
                                                   const float* __restrict__ attn,
                                                   const unsigned short* __restrict__ wbf,
                                                   const float* __restrict__ conv1_b,
                                                   const float* __restrict__ conv2_w,
                                                   const float* __restrict__ conv2_b,
                                                   float* __restrict__ depth_out,
                                                   float* __restrict__ logit_out) {
  __shared__ unsigned short xb[18*18*PADC];   // [row][col][ch], 25.9 KB
  __shared__ float s_attn[CIN];
  const int b  = blockIdx.z;
  const int h0 = blockIdx.y * 16, w0 = blockIdx.x * 16;
  const int tid = threadIdx.x;
  const int wv = tid >> 6, ln = tid & 63;
  const int lg = ln >> 4, lr = ln & 15;

  if (tid < CIN) s_attn[tid] = attn[b*CIN + tid];
  __syncthreads();

  f32x4 acc[4][4];
  #pragma unroll
  for (int mi = 0; mi < 4; mi++)
    #pragma unroll
    for (int ni = 0; ni < 4; ni++)
      acc[mi][ni] = (f32x4){0.f, 0.f, 0.f, 0.f};

  for (int c0 = 0; c0 < CIN; c0 += 32) {
    // stage bf16 input tile: xb[r*PADC + c] over r in [0,324), c in [0,32)
    for (int i = tid; i < 32*324; i += 256) {
      int c = i / 324;
      int r = i % 324;
      int rh = r / 18, rw = r % 18;
      int gh = h0 + rh - 1, gw = w0 + rw - 1;
      float v = 0.f;
      if (gh >= 0 && gh < HH && gw >= 0 && gw < WW)
        v = feat[((size_t)(b*CIN + c0 + c)*HH + gh)*WW + gw] * s_attn[c0 + c];
      xb[r*PADC + c] = rne_bf16(v);
    }
    __syncthreads();

    #pragma unroll
    for (int u = 0; u < 3; u++) {
      #pragma unroll
      for (int v = 0; v < 3; v++) {
        short8 bfr[4];
        #pragma unroll
        for (int ni = 0; ni < 4; ni++)
          bfr[ni] = *reinterpret_cast<const short8*>(
              wbf + ((size_t)(u*3+v)*OC + ni*16 + lr)*CIN + c0 + 8*lg);
        #pragma unroll
        for (int mi = 0; mi < 4; mi++) {
          short8 afr = *reinterpret_cast<const short8*>(
              &xb[((4*wv + mi + u)*18 + lr + v)*PADC + 8*lg]);
          #pragma unroll
          for (int ni = 0; ni < 4; ni++)
            acc[mi][ni] = __builtin_amdgcn_mfma_f32_16x16x32_bf16(
                afr, bfr[ni], acc[mi][ni], 0, 0, 0);
        }
      }
    }
    __syncthreads();
  }

  // epilogue: lane owns oc = ni*16 + lr, pixel cols 4*lg + q
  float bia[4], w20[4], w21[4];
  #pragma unroll
  for (int ni = 0; ni < 4; ni++) {
    int oc = ni*16 + lr;
    bia[ni] = conv1_b[oc];
    w20[ni] = conv2_w[oc];
    w21[ni] = conv2_w[OC + oc];
  }
  const float c2b0 = conv2_b[0], c2b1 = conv2_b[1];

  #pragma unroll
  for (int mi = 0; mi < 4; mi++) {
    const int gh = h0 + 4*wv + mi;
    #pragma unroll
    for (int q = 0; q < 4; q++) {
      float s0 = 0.f, s1 = 0.f;
      #pragma unroll
      for (int ni = 0; ni < 4; ni++) {
        float z = acc[mi][ni][q] + bia[ni];
        float g = 0.5f * z * (1.0f + erff(z * 0.70710678118654752f));
        s0 = fmaf(g, w20[ni], s0);
        s1 = fmaf(g, w21[ni], s1);
      }
      #pragma unroll
      for (int m = 1; m <= 8; m <<= 1) {
        s0 += __shfl_xor(s0, m, 64);
        s1 += __shfl_xor(s1, m, 64);
      }
      if (lr == 0) {
        const int gw = w0 + 4*lg + q;
        depth_out[((size_t)b*HH + gh)*WW + gw] = s0 + c2b0;
        logit_out[((size_t)b*HH + gh)*WW + gw] = s1 + c2b1;
      }
    }
  }
}

// ---------------- K4: per-batch softmax over HW (fp32, in place) + save max ----------------
__global__ __launch_bounds__(1024) void softmax_kernel(float* __restrict__ logits,
                                                       float* __restrict__ m_out) {
  const int b = blockIdx.x;
  float* lp = logits + (size_t)b * HW;
  const int tid = threadIdx.x;
  __shared__ float sred[16];
  __shared__ float s_m, s_z;

  float m = -INFINITY;
  for (int i = tid; i < HW; i += 1024) m = fmaxf(m, lp[i]);
  for (int off = 32; off > 0; off >>= 1) m = fmaxf(m, __shfl_down(m, off, 64));
  if ((tid & 63) == 0) sred[tid >> 6] = m;
  __syncthreads();
  if (tid == 0) {
    float t = sred[0];
    for (int i = 1; i < 16; i++) t = fmaxf(t, sred[i]);
    s_m = t;
    m_out[b] = t;
  }
  __syncthreads();
  m = s_m;

  float z = 0.f;
  for (int i = tid; i < HW; i += 1024) z += expf(lp[i] - m);
  __syncthreads();
  for (int off = 32; off > 0; off >>= 1) z += __shfl_down(z, off, 64);
  if ((tid & 63) == 0) sred[tid >> 6] = z;
  __syncthreads();
  if (tid == 0) {
    float t = 0.f;
    for (int i = 0; i < 16; i++) t += sred[i];
    s_z = t;
  }
  __syncthreads();
  z = s_z;

  for (int i = tid; i < HW; i += 1024) lp[i] = expf(lp[i] - m) / z;
}

// ---------------- K5: 3x3 box filter (zero pad) / 9, fp32 ----------------
__global__ __launch_bounds__(256) void box_kernel(const float* __restrict__ p,
                                                  float* __restrict__ out_f) {
  int i = blockIdx.x * 256 + threadIdx.x;
  if (i >= BATCH * HW) return;
  int b = i / HW, r = i % HW, h = r / WW, w = r % WW;
  const float* bp = p + (size_t)b * HW;
  float s = 0.f;
  for (int dy = -1; dy <= 1; dy++) {
    int h2 = h + dy;
    if (h2 < 0 || h2 >= HH) continue;
    for (int dx = -1; dx <= 1; dx++) {
      int w2 = w + dx;
      if (w2 < 0 || w2 >= WW) continue;
      s += bp[h2*WW + w2];
    }
  }
  out_f[i] = s / 9.0f;
}

// ---------------- K6: candidate selection (conf32 >= cut512*(1-3e-2)) ----------------
__global__ __launch_bounds__(1024) void cand_kernel(const float* __restrict__ conf,
                                                    int* __restrict__ cand_idx,
                                                    int* __restrict__ cand_cnt) {
  const int b = blockIdx.x;
  const float* cp = conf + (size_t)b * HW;
  const int tid = threadIdx.x;
  __shared__ unsigned sred[16];
  __shared__ unsigned s_total;
  __shared__ unsigned s_cnt;

  unsigned lo = 0u, hi = 0x7F800000u;   // conf > 0 always
  while (hi - lo > 1u) {
    unsigned mid = lo + ((hi - lo) >> 1);
    unsigned cnt = 0;
    for (int i = tid; i < HW; i += 1024)
      cnt += (__float_as_uint(cp[i]) >= mid) ? 1u : 0u;
    for (int off = 32; off > 0; off >>= 1) cnt += __shfl_down(cnt, off, 64);
    if ((tid & 63) == 0) sred[tid >> 6] = cnt;
    __syncthreads();
    if (tid == 0) {
      unsigned t = 0;
      for (int i = 0; i < 16; i++) t += sred[i];
      s_total = t;
    }
    __syncthreads();
    unsigned total = s_total;
    __syncthreads();
    if (total >= KPTS) lo = mid; else hi = mid;
  }
  float vcut = __uint_as_float(lo) * (1.0f - 3e-2f);

  if (tid == 0) s_cnt = 0;
  __syncthreads();
  for (int i = tid; i < HW; i += 1024) {
    if (cp[i] >= vcut) {
      unsigned s = atomicAdd(&s_cnt, 1u);
      if (s < CAP) cand_idx[b*CAP + s] = i;
    }
  }
  __syncthreads();
  if (tid == 0) cand_cnt[b] = (s_cnt < CAP) ? s_cnt : CAP;
}

// ---------------- K7: f64 refinement — score = sum_j exp64(l64_j - m32) ----------------
__global__ __launch_bounds__(256) void refine_kernel(const float* __restrict__ feat,
                                                     const double* __restrict__ attn_d,
                                                     const double* __restrict__ wd64,
                                                     const float* __restrict__ conv1_b,
                                                     const float* __restrict__ conv2_w,
                                                     const float* __restrict__ conv2_b,
                                                     const float* __restrict__ m32,
                                                     const int* __restrict__ cand_idx,
                                                     const int* __restrict__ cand_cnt,
                                                     double* __restrict__ cand_score) {
  const int b = blockIdx.y, slot = blockIdx.x;
  if (slot >= cand_cnt[b]) return;
  const int idx = cand_idx[b*CAP + slot];
  const int ph = idx / WW, pw = idx % WW;
  const int tid = threadIdx.x;

  __shared__ double xwin[CIN][25];
  __shared__ double part[4][9][64];
  __shared__ double cont[9][64];
  __shared__ double lval[9];

  for (int i = tid; i < CIN*25; i += 256) {
    int c = i / 25, rr = i % 25;
    int r = rr / 5, s = rr % 5;
    int gh = ph + r - 2, gw = pw + s - 2;
    float v = 0.f;
    if (gh >= 0 && gh < HH && gw >= 0 && gw < WW)
      v = feat[((size_t)(b*CIN + c)*HH + gh)*WW + gw];
    xwin[c][rr] = (double)v * attn_d[b*CIN + c];
  }
  __syncthreads();

  const int oc = tid & 63, cq = tid >> 6;
  double acc9[9];
  #pragma unroll
  for (int j = 0; j < 9; j++) acc9[j] = 0.0;
  const double* wp = wd64 + ((size_t)oc*CIN + cq*32) * 9;

  for (int ci = 0; ci < 32; ci++) {
    int c = cq*32 + ci;
    double xv[25];
    #pragma unroll
    for (int r = 0; r < 25; r++) xv[r] = xwin[c][r];
    #pragma unroll
    for (int k = 0; k < 9; k++) {
      double w = wp[ci*9 + k];
      const int u = k/3, v = k%3;
      #pragma unroll
      for (int j = 0; j < 9; j++) {
        const int a = j/3, bb = j%3;
        acc9[j] = fma(w, xv[(a+u)*5 + (bb+v)], acc9[j]);
      }
    }
  }
  #pragma unroll
  for (int j = 0; j < 9; j++) part[cq][j][oc] = acc9[j];
  __syncthreads();

  for (int t = tid; t < 576; t += 256) {
    int j = t >> 6, o = t & 63;
    double z = part[0][j][o] + part[1][j][o] + part[2][j][o] + part[3][j][o]
             + (double)conv1_b[o];
    double g = 0.5 * z * (1.0 + erf(z * 0.70710678118654752440));
    cont[j][o] = g * (double)conv2_w[OC + o];
  }
  __syncthreads();
  if (tid < 9) {
    double s = 0.0;
    for (int o = 0; o < 64; o++) s += cont[tid][o];
    lval[tid] = s + (double)conv2_b[1];
  }
  __syncthreads();
  if (tid == 0) {
    double m = (double)m32[b];
    double sc = 0.0;
    #pragma unroll
    for (int j = 0; j < 9; j++) {
      int a = j/3 - 1, bb = j%3 - 1;
      int qh = ph + a, qw = pw + bb;
      if (qh >= 0 && qh < HH && qw >= 0 && qw < WW)
        sc += exp(lval[j] - m);
    }
    cand_score[b*CAP + slot] = sc;
  }
}

// ---------------- K8: sort 2048 candidates (score desc, idx asc) + emit ----------------
__global__ __launch_bounds__(1024) void emit_kernel(const double* __restrict__ cand_score,
                                                    const int* __restrict__ cand_idx,
                                                    const int* __restrict__ cand_cnt,
                                                    const float* __restrict__ depth,
                                                    float* __restrict__ points) {
  const int b = blockIdx.x;
  const int tid = threadIdx.x;
  __shared__ double vals[CAP];
  __shared__ int    idxs[CAP];

  int cnt = cand_cnt[b];
  for (int i = tid; i < CAP; i += 1024) {
    if (i < cnt) { vals[i] = cand_score[b*CAP + i]; idxs[i] = cand_idx[b*CAP + i]; }
    else         { vals[i] = -1.0;                  idxs[i] = 0x7FFFFFFF; }
  }
  __syncthreads();

  for (unsigned k = 2; k <= CAP; k <<= 1) {
    for (unsigned j = k >> 1; j > 0; j >>= 1) {
      unsigned t = (unsigned)tid;           // one pair per thread (CAP/2 = 1024)
      unsigned i1 = ((t & ~(j - 1u)) << 1) | (t & (j - 1u));
      unsigned i2 = i1 | j;
      double v1 = vals[i1], v2 = vals[i2];
      int    a1 = idxs[i1], a2 = idxs[i2];
      bool oneAfterTwo = (v1 < v2) || (v1 == v2 && a1 > a2);
      bool descSeg = ((i1 & k) == 0);
      if (descSeg ? oneAfterTwo : !oneAfterTwo) {
        vals[i1] = v2; idxs[i1] = a2;
        vals[i2] = v1; idxs[i2] = a1;
      }
      __syncthreads();
    }
  }

  if (tid < KPTS) {
    int idx = idxs[tid];
    float d = depth[(size_t)b * HW + idx];
    float xi = (float)(idx % WW) / (float)WW;
    float yi = (float)(idx / WW) / (float)HH;
    float* pp = points + ((size_t)b * KPTS + tid) * 3;
    pp[0] = xi; pp[1] = yi; pp[2] = d;
  }
}

extern "C" void kernel_launch(void* const* d_in, const int* in_sizes, int n_in,
                              void* d_out, int out_size, void* d_ws, size_t ws_size,
                              hipStream_t stream) {
  const float* feat    = (const float*)d_in[0];
  const float* attn_w  = (const float*)d_in[1];
  const float* attn_b  = (const float*)d_in[2];
  const float* conv1_w = (const float*)d_in[3];
  const float* conv1_b = (const float*)d_in[4];
  const float* conv2_w = (const float*)d_in[5];
  const float* conv2_b = (const float*)d_in[6];

  float* out    = (float*)d_out;
  float* points = out;                          // 16*512*3
  float* depth  = out + 24576;                  // 16*36864
  float* conf_f = out + 24576 + BATCH*HW;       // 16*36864

  // ws layout: doubles, then floats, then bf16, then ints (all 16B-aligned)
  double* wsd        = (double*)d_ws;
  double* pool_d     = wsd;                                    // 2048
  double* attn_d     = wsd + 2048;                             // 2048
  double* wd64       = wsd + 4096;                             // 73728
  double* cand_score = wsd + 4096 + 73728;                     // 16*2048
  float*  wsf        = (float*)(cand_score + BATCH*CAP);
  float*  logit32    = wsf;                                    // 589824 (reused as probs)
  float*  attn_f     = logit32 + (size_t)BATCH*HW;             // 2048
  float*  m32        = attn_f + 2048;                          // 16
  unsigned short* wbf = (unsigned short*)(m32 + 16);           // 73728 bf16
  int*    cand_idx   = (int*)(wbf + OC*CIN*9);                 // 16*2048
  int*    cand_cnt   = cand_idx + BATCH*CAP;                   // 16

  pool_kernel<<<BATCH*CIN, 256, 0, stream>>>(feat, pool_d);
  attn_kernel<<<BATCH, CIN, 0, stream>>>(pool_d, attn_w, attn_b, attn_d, attn_f);
  wtrans_kernel<<<(OC*CIN*9 + 255)/256, 256, 0, stream>>>(conv1_w, wbf, wd64);
  dim3 cgrid(WW/16, HH/16, BATCH);
  conv_kernel<<<cgrid, 256, 0, stream>>>(feat, attn_f, wbf, conv1_b, conv2_w, conv2_b,
                                         depth, logit32);
  softmax_kernel<<<BATCH, 1024, 0, stream>>>(logit32, m32);   // in-place probs
  box_kernel<<<(BATCH*HW + 255)/256, 256, 0, stream>>>(logit32, conf_f);
  cand_kernel<<<BATCH, 1024, 0, stream>>>(conf_f, cand_idx, cand_cnt);
  refine_kernel<<<dim3(CAP, BATCH), 256, 0, stream>>>(feat, attn_d, wd64, conv1_b,
                                                      conv2_w, conv2_b, m32,
                                                      cand_idx, cand_cnt, cand_score);
  emit_kernel<<<BATCH, 1024, 0, stream>>>(cand_score, cand_idx, cand_cnt, depth, points);
}

// Round 5
// 1718.554 us; speedup vs baseline: 3.8244x; 1.3413x over previous
//
#include <hip/hip_runtime.h>
#include <math.h>

#define BATCH 16
#define CIN   128
#define HH    192
#define WW    192
#define HW    (HH*WW)
#define OC    64
#define KPTS  512
#define CAP   2048
#define UMAX  (CAP*9)
#define PPB   8
#define UPB   (UMAX/PPB)

typedef short short8 __attribute__((ext_vector_type(8)));
typedef float f32x4 __attribute__((ext_vector_type(4)));

__device__ __forceinline__ unsigned short rne_bf16(float v) {
  unsigned u = __float_as_uint(v);
  u += 0x7FFFu + ((u >> 16) & 1u);
  return (unsigned short)(u >> 16);
}

// ---------------- K1: global mean pool over H,W (f64 acc) ----------------
__global__ __launch_bounds__(256) void pool_kernel(const float* __restrict__ feat,
                                                   double* __restrict__ pool) {
  int bc = blockIdx.x;  // 0..2047
  const float4* fp = (const float4*)(feat + (size_t)bc * HW);
  double s = 0.0;
  for (int i = threadIdx.x; i < HW/4; i += 256) {
    float4 v = fp[i];
    s += (double)v.x + (double)v.y + (double)v.z + (double)v.w;
  }
  for (int off = 32; off > 0; off >>= 1) s += __shfl_down(s, off, 64);
  __shared__ double sb[4];
  int lane = threadIdx.x & 63, wv = threadIdx.x >> 6;
  if (lane == 0) sb[wv] = s;
  __syncthreads();
  if (threadIdx.x == 0) {
    double t = sb[0] + sb[1] + sb[2] + sb[3];
    pool[bc] = t / 36864.0;
  }
}

// ---------------- K2: attn = sigmoid(pool @ attn_w.T + attn_b) (f64 + f32 copy) ----------------
__global__ __launch_bounds__(128) void attn_kernel(const double* __restrict__ pool,
                                                   const float* __restrict__ attn_w,
                                                   const float* __restrict__ attn_b,
                                                   double* __restrict__ attn_d,
                                                   float* __restrict__ attn_f) {
  __shared__ double sp[CIN];
  int b = blockIdx.x, c = threadIdx.x;
  sp[c] = pool[b*CIN + c];
  __syncthreads();
  double s = (double)attn_b[c];
  const float* wr = attn_w + (size_t)c * CIN;
  for (int j = 0; j < CIN; j++) s = fma((double)wr[j], sp[j], s);
  double a = 1.0 / (1.0 + exp(-s));
  attn_d[b*CIN + c] = a;
  attn_f[b*CIN + c] = (float)a;
}

// ---------------- K2b: weights: wbf [tap][oc][c] bf16 ; w32T [c][tap][oc] f32 ----------------
__global__ __launch_bounds__(256) void wtrans_kernel(const float* __restrict__ w,
                                                     unsigned short* __restrict__ wbf,
                                                     float* __restrict__ w32T) {
  int i = blockIdx.x * 256 + threadIdx.x;
  if (i < OC*CIN*9) {
    int oc = i / (CIN*9);
    int r  = i % (CIN*9);
    int c  = r / 9;
    int k  = r % 9;
    float v = w[i];
    wbf[((size_t)k*OC + oc)*CIN + c] = rne_bf16(v);
    w32T[((size_t)c*9 + k)*OC + oc] = v;
  }
}

// ---------------- K3: MFMA conv3x3(128->64) + GeLU + conv1x1(64->2) ----------------
#define PADC 40
__global__ __launch_bounds__(256) void conv_kernel(const float* __restrict__ feat,
                                                   const float* __restrict__ attn,
                                                   const unsigned short* __restrict__ wbf,
                                                   const float* __restrict__ conv1_b,
                                                   const float* __restrict__ conv2_w,
                                                   const float* __restrict__ conv2_b,
                                                   float* __restrict__ depth_out,
                                                   float* __restrict__ logit_out) {
  __shared__ unsigned short xb[18*18*PADC];   // [row][col][ch], 25.9 KB
  __shared__ float s_attn[CIN];
  const int b  = blockIdx.z;
  const int h0 = blockIdx.y * 16, w0 = blockIdx.x * 16;
  const int tid = threadIdx.x;
  const int wv = tid >> 6, ln = tid & 63;
  const int lg = ln >> 4, lr = ln & 15;

  if (tid < CIN) s_attn[tid] = attn[b*CIN + tid];
  __syncthreads();

  f32x4 acc[4][4];
  #pragma unroll
  for (int mi = 0; mi < 4; mi++)
    #pragma unroll
    for (int ni = 0; ni < 4; ni++)
      acc[mi][ni] = (f32x4){0.f, 0.f, 0.f, 0.f};

  for (int c0 = 0; c0 < CIN; c0 += 32) {
    for (int i = tid; i < 32*324; i += 256) {
      int c = i / 324;
      int r = i % 324;
      int rh = r / 18, rw = r % 18;
      int gh = h0 + rh - 1, gw = w0 + rw - 1;
      float v = 0.f;
      if (gh >= 0 && gh < HH && gw >= 0 && gw < WW)
        v = feat[((size_t)(b*CIN + c0 + c)*HH + gh)*WW + gw] * s_attn[c0 + c];
      xb[r*PADC + c] = rne_bf16(v);
    }
    __syncthreads();

    #pragma unroll
    for (int u = 0; u < 3; u++) {
      #pragma unroll
      for (int v = 0; v < 3; v++) {
        short8 bfr[4];
        #pragma unroll
        for (int ni = 0; ni < 4; ni++)
          bfr[ni] = *reinterpret_cast<const short8*>(
              wbf + ((size_t)(u*3+v)*OC + ni*16 + lr)*CIN + c0 + 8*lg);
        #pragma unroll
        for (int mi = 0; mi < 4; mi++) {
          short8 afr = *reinterpret_cast<const short8*>(
              &xb[((4*wv + mi + u)*18 + lr + v)*PADC + 8*lg]);
          #pragma unroll
          for (int ni = 0; ni < 4; ni++)
            acc[mi][ni] = __builtin_amdgcn_mfma_f32_16x16x32_bf16(
                afr, bfr[ni], acc[mi][ni], 0, 0, 0);
        }
      }
    }
    __syncthreads();
  }

  float bia[4], w20[4], w21[4];
  #pragma unroll
  for (int ni = 0; ni < 4; ni++) {
    int oc = ni*16 + lr;
    bia[ni] = conv1_b[oc];
    w20[ni] = conv2_w[oc];
    w21[ni] = conv2_w[OC + oc];
  }
  const float c2b0 = conv2_b[0], c2b1 = conv2_b[1];

  #pragma unroll
  for (int mi = 0; mi < 4; mi++) {
    const int gh = h0 + 4*wv + mi;
    #pragma unroll
    for (int q = 0; q < 4; q++) {
      float s0 = 0.f, s1 = 0.f;
      #pragma unroll
      for (int ni = 0; ni < 4; ni++) {
        float z = acc[mi][ni][q] + bia[ni];
        float g = 0.5f * z * (1.0f + erff(z * 0.70710678118654752f));
        s0 = fmaf(g, w20[ni], s0);
        s1 = fmaf(g, w21[ni], s1);
      }
      #pragma unroll
      for (int m = 1; m <= 8; m <<= 1) {
        s0 += __shfl_xor(s0, m, 64);
        s1 += __shfl_xor(s1, m, 64);
      }
      if (lr == 0) {
        const int gw = w0 + 4*lg + q;
        depth_out[((size_t)b*HH + gh)*WW + gw] = s0 + c2b0;
        logit_out[((size_t)b*HH + gh)*WW + gw] = s1 + c2b1;
      }
    }
  }
}

// ---------------- K4: per-batch softmax over HW (fp32, in place) + save max ----------------
__global__ __launch_bounds__(1024) void softmax_kernel(float* __restrict__ logits,
                                                       float* __restrict__ m_out) {
  const int b = blockIdx.x;
  float* lp = logits + (size_t)b * HW;
  const int tid = threadIdx.x;
  __shared__ float sred[16];
  __shared__ float s_m, s_z;

  float m = -INFINITY;
  for (int i = tid; i < HW; i += 1024) m = fmaxf(m, lp[i]);
  for (int off = 32; off > 0; off >>= 1) m = fmaxf(m, __shfl_down(m, off, 64));
  if ((tid & 63) == 0) sred[tid >> 6] = m;
  __syncthreads();
  if (tid == 0) {
    float t = sred[0];
    for (int i = 1; i < 16; i++) t = fmaxf(t, sred[i]);
    s_m = t;
    m_out[b] = t;
  }
  __syncthreads();
  m = s_m;

  float z = 0.f;
  for (int i = tid; i < HW; i += 1024) z += expf(lp[i] - m);
  __syncthreads();
  for (int off = 32; off > 0; off >>= 1) z += __shfl_down(z, off, 64);
  if ((tid & 63) == 0) sred[tid >> 6] = z;
  __syncthreads();
  if (tid == 0) {
    float t = 0.f;
    for (int i = 0; i < 16; i++) t += sred[i];
    s_z = t;
  }
  __syncthreads();
  z = s_z;

  for (int i = tid; i < HW; i += 1024) lp[i] = expf(lp[i] - m) / z;
}

// ---------------- K5: 3x3 box filter (zero pad) / 9, fp32 ----------------
__global__ __launch_bounds__(256) void box_kernel(const float* __restrict__ p,
                                                  float* __restrict__ out_f) {
  int i = blockIdx.x * 256 + threadIdx.x;
  if (i >= BATCH * HW) return;
  int b = i / HW, r = i % HW, h = r / WW, w = r % WW;
  const float* bp = p + (size_t)b * HW;
  float s = 0.f;
  for (int dy = -1; dy <= 1; dy++) {
    int h2 = h + dy;
    if (h2 < 0 || h2 >= HH) continue;
    for (int dx = -1; dx <= 1; dx++) {
      int w2 = w + dx;
      if (w2 < 0 || w2 >= WW) continue;
      s += bp[h2*WW + w2];
    }
  }
  out_f[i] = s / 9.0f;
}

// ---------------- K6: candidates + union-of-neighborhood unique pixel list ----------------
__global__ __launch_bounds__(1024) void cand_kernel(const float* __restrict__ conf,
                                                    int* __restrict__ cand_idx,
                                                    int* __restrict__ cand_cnt,
                                                    int* __restrict__ upix,
                                                    int* __restrict__ upix_cnt) {
  const int b = blockIdx.x;
  const float* cp = conf + (size_t)b * HW;
  const int tid = threadIdx.x;
  __shared__ unsigned sred[16];
  __shared__ unsigned s_total;
  __shared__ unsigned s_cnt;
  __shared__ unsigned bm[1152];     // 36864-bit map
  __shared__ unsigned pcs[1152];
  __shared__ unsigned grpoff[37];

  unsigned lo = 0u, hi = 0x7F800000u;   // conf > 0 always
  while (hi - lo > 1u) {
    unsigned mid = lo + ((hi - lo) >> 1);
    unsigned cnt = 0;
    for (int i = tid; i < HW; i += 1024)
      cnt += (__float_as_uint(cp[i]) >= mid) ? 1u : 0u;
    for (int off = 32; off > 0; off >>= 1) cnt += __shfl_down(cnt, off, 64);
    if ((tid & 63) == 0) sred[tid >> 6] = cnt;
    __syncthreads();
    if (tid == 0) {
      unsigned t = 0;
      for (int i = 0; i < 16; i++) t += sred[i];
      s_total = t;
    }
    __syncthreads();
    unsigned total = s_total;
    __syncthreads();
    if (total >= KPTS) lo = mid; else hi = mid;
  }
  float vcut = __uint_as_float(lo) * (1.0f - 3e-2f);

  if (tid == 0) s_cnt = 0;
  for (int i = tid; i < 1152; i += 1024) bm[i] = 0u;
  __syncthreads();

  for (int i = tid; i < HW; i += 1024) {
    if (cp[i] >= vcut) {
      unsigned s = atomicAdd(&s_cnt, 1u);
      if (s < CAP) {
        cand_idx[b*CAP + s] = i;
        int h = i / WW, w = i % WW;
        for (int dy = -1; dy <= 1; dy++) {
          int qh = h + dy;
          if (qh < 0 || qh >= HH) continue;
          for (int dx = -1; dx <= 1; dx++) {
            int qw = w + dx;
            if (qw < 0 || qw >= WW) continue;
            int q = qh*WW + qw;
            atomicOr(&bm[q >> 5], 1u << (q & 31));
          }
        }
      }
    }
  }
  __syncthreads();
  if (tid == 0) cand_cnt[b] = (s_cnt < CAP) ? s_cnt : CAP;

  // compact bitmap -> upix list
  for (int i = tid; i < 1152; i += 1024) pcs[i] = __popc(bm[i]);
  __syncthreads();
  if (tid < 36) {
    unsigned s = 0;
    for (int j = 0; j < 32; j++) s += pcs[tid*32 + j];
    grpoff[tid] = s;
  }
  __syncthreads();
  if (tid == 0) {
    unsigned run = 0;
    for (int g = 0; g < 36; g++) { unsigned t = grpoff[g]; grpoff[g] = run; run += t; }
    grpoff[36] = run;
    upix_cnt[b] = (int)run;
  }
  __syncthreads();
  for (int i = tid; i < 1152; i += 1024) {
    unsigned off = grpoff[i >> 5];
    for (int w = (i & ~31); w < i; w++) off += pcs[w];
    unsigned u = bm[i];
    while (u) {
      int bit = __ffs(u) - 1;
      u &= u - 1u;
      upix[b*UMAX + off++] = i*32 + bit;
    }
  }
}

// ---------------- K7a: f64 logit for each unique pixel -> lmap ----------------
__global__ __launch_bounds__(256) void logit_kernel(const float* __restrict__ feat,
                                                    const double* __restrict__ attn_d,
                                                    const float* __restrict__ w32T,
                                                    const float* __restrict__ conv1_b,
                                                    const float* __restrict__ conv2_w,
                                                    const float* __restrict__ conv2_b,
                                                    const int* __restrict__ upix,
                                                    const int* __restrict__ upix_cnt,
                                                    double* __restrict__ lmap) {
  const int b = blockIdx.y;
  const int base = blockIdx.x * PPB;
  const int ucnt = upix_cnt[b];
  if (base >= ucnt) return;
  const int rem = min(PPB, ucnt - base);
  const int tid = threadIdx.x;

  __shared__ double xw[PPB][CIN*9];   // 73.7 KB : x64 = f64(feat)*attn64, [p][c*9+k]
  __shared__ double s_attn[CIN];
  __shared__ int    s_pix[PPB];

  if (tid < CIN) s_attn[tid] = attn_d[b*CIN + tid];
  if (tid < PPB) s_pix[tid] = (tid < rem) ? upix[b*UMAX + base + tid] : 0;
  __syncthreads();

  for (int i = tid; i < PPB*CIN*9; i += 256) {
    int p = i / (CIN*9);
    int r = i % (CIN*9);
    int c = r / 9, k = r % 9;
    double v = 0.0;
    if (p < rem) {
      int pix = s_pix[p];
      int gh = pix / WW + k/3 - 1, gw = pix % WW + k%3 - 1;
      if (gh >= 0 && gh < HH && gw >= 0 && gw < WW)
        v = (double)feat[((size_t)(b*CIN + c)*HH + gh)*WW + gw] * s_attn[c];
    }
    xw[p][r] = v;
  }
  __syncthreads();

  const int oc = tid & 63;      // lane
  const int pg = tid >> 6;      // wave -> pixel pair {2pg, 2pg+1}
  double acc0 = 0.0, acc1 = 0.0;
  const int p0 = 2*pg, p1 = 2*pg + 1;

  for (int c = 0; c < CIN; c++) {
    const float* wp = w32T + ((size_t)c*9)*OC + oc;
    const double* x0 = &xw[p0][c*9];
    const double* x1 = &xw[p1][c*9];
    #pragma unroll
    for (int k = 0; k < 9; k++) {
      double w = (double)wp[k*OC];
      acc0 = fma(w, x0[k], acc0);
      acc1 = fma(w, x1[k], acc1);
    }
  }

  // epilogue: z -> gelu -> * conv2_w[1][oc]; reduce over 64 lanes
  double zb = (double)conv1_b[oc];
  double w1 = (double)conv2_w[OC + oc];
  double z0 = acc0 + zb, z1 = acc1 + zb;
  double g0 = 0.5 * z0 * (1.0 + erf(z0 * 0.70710678118654752440));
  double g1 = 0.5 * z1 * (1.0 + erf(z1 * 0.70710678118654752440));
  double c0 = g0 * w1, c1 = g1 * w1;
  #pragma unroll
  for (int m = 1; m <= 32; m <<= 1) {
    c0 += __shfl_xor(c0, m, 64);
    c1 += __shfl_xor(c1, m, 64);
  }
  if (oc == 0) {
    double bb = (double)conv2_b[1];
    if (p0 < rem) lmap[(size_t)b*HW + s_pix[p0]] = c0 + bb;
    if (p1 < rem) lmap[(size_t)b*HW + s_pix[p1]] = c1 + bb;
  }
}

// ---------------- K7b: per-candidate score = sum_j exp64(lmap_j - m32) ----------------
__global__ __launch_bounds__(256) void score_kernel(const double* __restrict__ lmap,
                                                    const float* __restrict__ m32,
                                                    const int* __restrict__ cand_idx,
                                                    const int* __restrict__ cand_cnt,
                                                    double* __restrict__ cand_score) {
  const int b = blockIdx.y;
  const int slot = blockIdx.x * 256 + threadIdx.x;
  if (slot >= cand_cnt[b]) return;
  const int idx = cand_idx[b*CAP + slot];
  const int ph = idx / WW, pw = idx % WW;
  const double m = (double)m32[b];
  double s = 0.0;
  for (int dy = -1; dy <= 1; dy++) {
    int qh = ph + dy;
    if (qh < 0 || qh >= HH) continue;
    for (int dx = -1; dx <= 1; dx++) {
      int qw = pw + dx;
      if (qw < 0 || qw >= WW) continue;
      s += exp(lmap[(size_t)b*HW + qh*WW + qw] - m);
    }
  }
  cand_score[b*CAP + slot] = s;
}

// ---------------- K8: sort 2048 candidates (score desc, idx asc) + emit ----------------
__global__ __launch_bounds__(1024) void emit_kernel(const double* __restrict__ cand_score,
                                                    const int* __restrict__ cand_idx,
                                                    const int* __restrict__ cand_cnt,
                                                    const float* __restrict__ depth,
                                                    float* __restrict__ points) {
  const int b = blockIdx.x;
  const int tid = threadIdx.x;
  __shared__ double vals[CAP];
  __shared__ int    idxs[CAP];

  int cnt = cand_cnt[b];
  for (int i = tid; i < CAP; i += 1024) {
    if (i < cnt) { vals[i] = cand_score[b*CAP + i]; idxs[i] = cand_idx[b*CAP + i]; }
    else         { vals[i] = -1.0;                  idxs[i] = 0x7FFFFFFF; }
  }
  __syncthreads();

  for (unsigned k = 2; k <= CAP; k <<= 1) {
    for (unsigned j = k >> 1; j > 0; j >>= 1) {
      unsigned t = (unsigned)tid;           // one pair per thread (CAP/2 = 1024)
      unsigned i1 = ((t & ~(j - 1u)) << 1) | (t & (j - 1u));
      unsigned i2 = i1 | j;
      double v1 = vals[i1], v2 = vals[i2];
      int    a1 = idxs[i1], a2 = idxs[i2];
      bool oneAfterTwo = (v1 < v2) || (v1 == v2 && a1 > a2);
      bool descSeg = ((i1 & k) == 0);
      if (descSeg ? oneAfterTwo : !oneAfterTwo) {
        vals[i1] = v2; idxs[i1] = a2;
        vals[i2] = v1; idxs[i2] = a1;
      }
      __syncthreads();
    }
  }

  if (tid < KPTS) {
    int idx = idxs[tid];
    float d = depth[(size_t)b * HW + idx];
    float xi = (float)(idx % WW) / (float)WW;
    float yi = (float)(idx / WW) / (float)HH;
    float* pp = points + ((size_t)b * KPTS + tid) * 3;
    pp[0] = xi; pp[1] = yi; pp[2] = d;
  }
}

extern "C" void kernel_launch(void* const* d_in, const int* in_sizes, int n_in,
                              void* d_out, int out_size, void* d_ws, size_t ws_size,
                              hipStream_t stream) {
  const float* feat    = (const float*)d_in[0];
  const float* attn_w  = (const float*)d_in[1];
  const float* attn_b  = (const float*)d_in[2];
  const float* conv1_w = (const float*)d_in[3];
  const float* conv1_b = (const float*)d_in[4];
  const float* conv2_w = (const float*)d_in[5];
  const float* conv2_b = (const float*)d_in[6];

  float* out    = (float*)d_out;
  float* points = out;                          // 16*512*3
  float* depth  = out + 24576;                  // 16*36864
  float* conf_f = out + 24576 + BATCH*HW;       // 16*36864

  // ws layout: doubles, then floats, then bf16, then ints  (~9.2 MB)
  double* wsd        = (double*)d_ws;
  double* pool_d     = wsd;                                    // 2048
  double* attn_d     = wsd + 2048;                             // 2048
  double* cand_score = wsd + 4096;                             // 16*2048
  double* lmap       = cand_score + BATCH*CAP;                 // 16*36864
  float*  wsf        = (float*)(lmap + (size_t)BATCH*HW);
  float*  logit32    = wsf;                                    // 589824 (reused as probs)
  float*  attn_f     = logit32 + (size_t)BATCH*HW;             // 2048
  float*  m32        = attn_f + 2048;                          // 16
  float*  w32T       = m32 + 16;                               // 73728
  unsigned short* wbf = (unsigned short*)(w32T + OC*CIN*9);    // 73728 bf16
  int*    cand_idx   = (int*)(wbf + OC*CIN*9);                 // 16*2048
  int*    cand_cnt   = cand_idx + BATCH*CAP;                   // 16
  int*    upix       = cand_cnt + 16;                          // 16*18432
  int*    upix_cnt   = upix + BATCH*UMAX;                      // 16

  pool_kernel<<<BATCH*CIN, 256, 0, stream>>>(feat, pool_d);
  attn_kernel<<<BATCH, CIN, 0, stream>>>(pool_d, attn_w, attn_b, attn_d, attn_f);
  wtrans_kernel<<<(OC*CIN*9 + 255)/256, 256, 0, stream>>>(conv1_w, wbf, w32T);
  dim3 cgrid(WW/16, HH/16, BATCH);
  conv_kernel<<<cgrid, 256, 0, stream>>>(feat, attn_f, wbf, conv1_b, conv2_w, conv2_b,
                                         depth, logit32);
  softmax_kernel<<<BATCH, 1024, 0, stream>>>(logit32, m32);   // in-place probs
  box_kernel<<<(BATCH*HW + 255)/256, 256, 0, stream>>>(logit32, conf_f);
  cand_kernel<<<BATCH, 1024, 0, stream>>>(conf_f, cand_idx, cand_cnt, upix, upix_cnt);
  logit_kernel<<<dim3(UPB, BATCH), 256, 0, stream>>>(feat, attn_d, w32T, conv1_b,
                                                     conv2_w, conv2_b, upix, upix_cnt, lmap);
  score_kernel<<<dim3(CAP/256, BATCH), 256, 0, stream>>>(lmap, m32, cand_idx, cand_cnt,
                                                         cand_score);
  emit_kernel<<<BATCH, 1024, 0, stream>>>(cand_score, cand_idx, cand_cnt, depth, points);
}

// Round 6
// 1622.555 us; speedup vs baseline: 4.0507x; 1.0592x over previous
//
#include <hip/hip_runtime.h>
#include <math.h>

#define BATCH 16
#define CIN   128
#define HH    192
#define WW    192
#define HW    (HH*WW)
#define OC    64
#define KPTS  512
#define CAP   2048
#define UMAX  (CAP*9)
#define UPB4  (UMAX/4)

typedef short short8 __attribute__((ext_vector_type(8)));
typedef float f32x4 __attribute__((ext_vector_type(4)));

__device__ __forceinline__ unsigned short rne_bf16(float v) {
  unsigned u = __float_as_uint(v);
  u += 0x7FFFu + ((u >> 16) & 1u);
  return (unsigned short)(u >> 16);
}

// ---------------- K1: global mean pool over H,W (f64 acc) ----------------
__global__ __launch_bounds__(256) void pool_kernel(const float* __restrict__ feat,
                                                   double* __restrict__ pool) {
  int bc = blockIdx.x;  // 0..2047
  const float4* fp = (const float4*)(feat + (size_t)bc * HW);
  double s = 0.0;
  for (int i = threadIdx.x; i < HW/4; i += 256) {
    float4 v = fp[i];
    s += (double)v.x + (double)v.y + (double)v.z + (double)v.w;
  }
  for (int off = 32; off > 0; off >>= 1) s += __shfl_down(s, off, 64);
  __shared__ double sb[4];
  int lane = threadIdx.x & 63, wv = threadIdx.x >> 6;
  if (lane == 0) sb[wv] = s;
  __syncthreads();
  if (threadIdx.x == 0) {
    double t = sb[0] + sb[1] + sb[2] + sb[3];
    pool[bc] = t / 36864.0;
  }
}

// ---------------- K2: attn = sigmoid(pool @ attn_w.T + attn_b) (f64 + f32 copy) ----------------
__global__ __launch_bounds__(128) void attn_kernel(const double* __restrict__ pool,
                                                   const float* __restrict__ attn_w,
                                                   const float* __restrict__ attn_b,
                                                   double* __restrict__ attn_d,
                                                   float* __restrict__ attn_f) {
  __shared__ double sp[CIN];
  int b = blockIdx.x, c = threadIdx.x;
  sp[c] = pool[b*CIN + c];
  __syncthreads();
  double s = (double)attn_b[c];
  const float* wr = attn_w + (size_t)c * CIN;
  for (int j = 0; j < CIN; j++) s = fma((double)wr[j], sp[j], s);
  double a = 1.0 / (1.0 + exp(-s));
  attn_d[b*CIN + c] = a;
  attn_f[b*CIN + c] = (float)a;
}

// ---------------- K2b: weights: wbf [tap][oc][c] bf16 ; w9 [c][oc][12] f32 ----------------
__global__ __launch_bounds__(256) void wtrans_kernel(const float* __restrict__ w,
                                                     unsigned short* __restrict__ wbf,
                                                     float* __restrict__ w9) {
  int i = blockIdx.x * 256 + threadIdx.x;
  if (i < OC*CIN*9) {
    int oc = i / (CIN*9);
    int r  = i % (CIN*9);
    int c  = r / 9;
    int k  = r % 9;
    float v = w[i];
    wbf[((size_t)k*OC + oc)*CIN + c] = rne_bf16(v);
    w9[((size_t)c*OC + oc)*12 + k] = v;
  }
}

// ---------------- K3: MFMA conv3x3(128->64) + GeLU + conv1x1(64->2) ----------------
#define PADC 40
__global__ __launch_bounds__(256) void conv_kernel(const float* __restrict__ feat,
                                                   const float* __restrict__ attn,
                                                   const unsigned short* __restrict__ wbf,
                                                   const float* __restrict__ conv1_b,
                                                   const float* __restrict__ conv2_w,
                                                   const float* __restrict__ conv2_b,
                                                   float* __restrict__ depth_out,
                                                   float* __restrict__ logit_out) {
  __shared__ unsigned short xb[18*18*PADC];   // [row][col][ch], 25.9 KB
  __shared__ float s_attn[CIN];
  const int b  = blockIdx.z;
  const int h0 = blockIdx.y * 16, w0 = blockIdx.x * 16;
  const int tid = threadIdx.x;
  const int wv = tid >> 6, ln = tid & 63;
  const int lg = ln >> 4, lr = ln & 15;

  if (tid < CIN) s_attn[tid] = attn[b*CIN + tid];
  __syncthreads();

  f32x4 acc[4][4];
  #pragma unroll
  for (int mi = 0; mi < 4; mi++)
    #pragma unroll
    for (int ni = 0; ni < 4; ni++)
      acc[mi][ni] = (f32x4){0.f, 0.f, 0.f, 0.f};

  for (int c0 = 0; c0 < CIN; c0 += 32) {
    for (int i = tid; i < 32*324; i += 256) {
      int c = i / 324;
      int r = i % 324;
      int rh = r / 18, rw = r % 18;
      int gh = h0 + rh - 1, gw = w0 + rw - 1;
      float v = 0.f;
      if (gh >= 0 && gh < HH && gw >= 0 && gw < WW)
        v = feat[((size_t)(b*CIN + c0 + c)*HH + gh)*WW + gw] * s_attn[c0 + c];
      xb[r*PADC + c] = rne_bf16(v);
    }
    __syncthreads();

    #pragma unroll
    for (int u = 0; u < 3; u++) {
      #pragma unroll
      for (int v = 0; v < 3; v++) {
        short8 bfr[4];
        #pragma unroll
        for (int ni = 0; ni < 4; ni++)
          bfr[ni] = *reinterpret_cast<const short8*>(
              wbf + ((size_t)(u*3+v)*OC + ni*16 + lr)*CIN + c0 + 8*lg);
        #pragma unroll
        for (int mi = 0; mi < 4; mi++) {
          short8 afr = *reinterpret_cast<const short8*>(
              &xb[((4*wv + mi + u)*18 + lr + v)*PADC + 8*lg]);
          #pragma unroll
          for (int ni = 0; ni < 4; ni++)
            acc[mi][ni] = __builtin_amdgcn_mfma_f32_16x16x32_bf16(
                afr, bfr[ni], acc[mi][ni], 0, 0, 0);
        }
      }
    }
    __syncthreads();
  }

  float bia[4], w20[4], w21[4];
  #pragma unroll
  for (int ni = 0; ni < 4; ni++) {
    int oc = ni*16 + lr;
    bia[ni] = conv1_b[oc];
    w20[ni] = conv2_w[oc];
    w21[ni] = conv2_w[OC + oc];
  }
  const float c2b0 = conv2_b[0], c2b1 = conv2_b[1];

  #pragma unroll
  for (int mi = 0; mi < 4; mi++) {
    const int gh = h0 + 4*wv + mi;
    #pragma unroll
    for (int q = 0; q < 4; q++) {
      float s0 = 0.f, s1 = 0.f;
      #pragma unroll
      for (int ni = 0; ni < 4; ni++) {
        float z = acc[mi][ni][q] + bia[ni];
        float g = 0.5f * z * (1.0f + erff(z * 0.70710678118654752f));
        s0 = fmaf(g, w20[ni], s0);
        s1 = fmaf(g, w21[ni], s1);
      }
      #pragma unroll
      for (int m = 1; m <= 8; m <<= 1) {
        s0 += __shfl_xor(s0, m, 64);
        s1 += __shfl_xor(s1, m, 64);
      }
      if (lr == 0) {
        const int gw = w0 + 4*lg + q;
        depth_out[((size_t)b*HH + gh)*WW + gw] = s0 + c2b0;
        logit_out[((size_t)b*HH + gh)*WW + gw] = s1 + c2b1;
      }
    }
  }
}

// ---------------- K4: per-batch softmax over HW (fp32, in place) + save max ----------------
__global__ __launch_bounds__(1024) void softmax_kernel(float* __restrict__ logits,
                                                       float* __restrict__ m_out) {
  const int b = blockIdx.x;
  float* lp = logits + (size_t)b * HW;
  const int tid = threadIdx.x;
  __shared__ float sred[16];
  __shared__ float s_m, s_z;

  float m = -INFINITY;
  for (int i = tid; i < HW; i += 1024) m = fmaxf(m, lp[i]);
  for (int off = 32; off > 0; off >>= 1) m = fmaxf(m, __shfl_down(m, off, 64));
  if ((tid & 63) == 0) sred[tid >> 6] = m;
  __syncthreads();
  if (tid == 0) {
    float t = sred[0];
    for (int i = 1; i < 16; i++) t = fmaxf(t, sred[i]);
    s_m = t;
    m_out[b] = t;
  }
  __syncthreads();
  m = s_m;

  float z = 0.f;
  for (int i = tid; i < HW; i += 1024) z += expf(lp[i] - m);
  __syncthreads();
  for (int off = 32; off > 0; off >>= 1) z += __shfl_down(z, off, 64);
  if ((tid & 63) == 0) sred[tid >> 6] = z;
  __syncthreads();
  if (tid == 0) {
    float t = 0.f;
    for (int i = 0; i < 16; i++) t += sred[i];
    s_z = t;
  }
  __syncthreads();
  z = s_z;

  for (int i = tid; i < HW; i += 1024) lp[i] = expf(lp[i] - m) / z;
}

// ---------------- K5: 3x3 box filter (zero pad) / 9, fp32 ----------------
__global__ __launch_bounds__(256) void box_kernel(const float* __restrict__ p,
                                                  float* __restrict__ out_f) {
  int i = blockIdx.x * 256 + threadIdx.x;
  if (i >= BATCH * HW) return;
  int b = i / HW, r = i % HW, h = r / WW, w = r % WW;
  const float* bp = p + (size_t)b * HW;
  float s = 0.f;
  for (int dy = -1; dy <= 1; dy++) {
    int h2 = h + dy;
    if (h2 < 0 || h2 >= HH) continue;
    for (int dx = -1; dx <= 1; dx++) {
      int w2 = w + dx;
      if (w2 < 0 || w2 >= WW) continue;
      s += bp[h2*WW + w2];
    }
  }
  out_f[i] = s / 9.0f;
}

// ---------------- K6: candidates + union-of-neighborhood unique pixel list ----------------
__global__ __launch_bounds__(1024) void cand_kernel(const float* __restrict__ conf,
                                                    int* __restrict__ cand_idx,
                                                    int* __restrict__ cand_cnt,
                                                    int* __restrict__ upix,
                                                    int* __restrict__ upix_cnt) {
  const int b = blockIdx.x;
  const float* cp = conf + (size_t)b * HW;
  const int tid = threadIdx.x;
  __shared__ unsigned sred[16];
  __shared__ unsigned s_total;
  __shared__ unsigned s_cnt;
  __shared__ unsigned bm[1152];     // 36864-bit map
  __shared__ unsigned pcs[1152];
  __shared__ unsigned grpoff[37];

  unsigned lo = 0u, hi = 0x7F800000u;   // conf > 0 always
  while (hi - lo > 1u) {
    unsigned mid = lo + ((hi - lo) >> 1);
    unsigned cnt = 0;
    for (int i = tid; i < HW; i += 1024)
      cnt += (__float_as_uint(cp[i]) >= mid) ? 1u : 0u;
    for (int off = 32; off > 0; off >>= 1) cnt += __shfl_down(cnt, off, 64);
    if ((tid & 63) == 0) sred[tid >> 6] = cnt;
    __syncthreads();
    if (tid == 0) {
      unsigned t = 0;
      for (int i = 0; i < 16; i++) t += sred[i];
      s_total = t;
    }
    __syncthreads();
    unsigned total = s_total;
    __syncthreads();
    if (total >= KPTS) lo = mid; else hi = mid;
  }
  float vcut = __uint_as_float(lo) * (1.0f - 3e-2f);

  if (tid == 0) s_cnt = 0;
  for (int i = tid; i < 1152; i += 1024) bm[i] = 0u;
  __syncthreads();

  for (int i = tid; i < HW; i += 1024) {
    if (cp[i] >= vcut) {
      unsigned s = atomicAdd(&s_cnt, 1u);
      if (s < CAP) {
        cand_idx[b*CAP + s] = i;
        int h = i / WW, w = i % WW;
        for (int dy = -1; dy <= 1; dy++) {
          int qh = h + dy;
          if (qh < 0 || qh >= HH) continue;
          for (int dx = -1; dx <= 1; dx++) {
            int qw = w + dx;
            if (qw < 0 || qw >= WW) continue;
            int q = qh*WW + qw;
            atomicOr(&bm[q >> 5], 1u << (q & 31));
          }
        }
      }
    }
  }
  __syncthreads();
  if (tid == 0) cand_cnt[b] = (s_cnt < CAP) ? s_cnt : CAP;

  for (int i = tid; i < 1152; i += 1024) pcs[i] = __popc(bm[i]);
  __syncthreads();
  if (tid < 36) {
    unsigned s = 0;
    for (int j = 0; j < 32; j++) s += pcs[tid*32 + j];
    grpoff[tid] = s;
  }
  __syncthreads();
  if (tid == 0) {
    unsigned run = 0;
    for (int g = 0; g < 36; g++) { unsigned t = grpoff[g]; grpoff[g] = run; run += t; }
    grpoff[36] = run;
    upix_cnt[b] = (int)run;
  }
  __syncthreads();
  for (int i = tid; i < 1152; i += 1024) {
    unsigned off = grpoff[i >> 5];
    for (int w = (i & ~31); w < i; w++) off += pcs[w];
    unsigned u = bm[i];
    while (u) {
      int bit = __ffs(u) - 1;
      u &= u - 1u;
      upix[b*UMAX + off++] = i*32 + bit;
    }
  }
}

// ---------------- K7a: f64 logit per unique pixel; 4 pixels/block, c-split over waves ----------------
__global__ __launch_bounds__(256) void logit_kernel(const float* __restrict__ feat,
                                                    const double* __restrict__ attn_d,
                                                    const float* __restrict__ w9,
                                                    const float* __restrict__ conv1_b,
                                                    const float* __restrict__ conv2_w,
                                                    const float* __restrict__ conv2_b,
                                                    const int* __restrict__ upix,
                                                    const int* __restrict__ upix_cnt,
                                                    double* __restrict__ lmap) {
  // XCD-aware bijective swizzle (grid = 16*UPB4 = 73728, % 8 == 0)
  const int nb = BATCH * UPB4;
  int bid = blockIdx.x;
  int swz = (bid & 7) * (nb >> 3) + (bid >> 3);
  const int b = swz / UPB4;
  const int base4 = (swz % UPB4) * 4;
  const int ucnt = upix_cnt[b];
  if (base4 >= ucnt) return;
  const int rem = min(4, ucnt - base4);
  const int tid = threadIdx.x;

  __shared__ double xw[4][1152];      // 36.9 KB : x64 = f64(feat)*attn64, [p][c*9+k]
  __shared__ double s_attn[CIN];      // 1 KB
  __shared__ double part[4][4][64];   // 8 KB  [cq][p][oc]
  __shared__ int    s_pix[4];

  if (tid < CIN) s_attn[tid] = attn_d[b*CIN + tid];
  if (tid < 4) s_pix[tid] = (tid < rem) ? upix[b*UMAX + base4 + tid] : 0;
  __syncthreads();

  for (int i = tid; i < 4*1152; i += 256) {
    int p = i / 1152, r = i % 1152;
    int c = r / 9, k = r % 9;
    double v = 0.0;
    if (p < rem) {
      int pix = s_pix[p];
      int gh = pix / WW + k/3 - 1, gw = pix % WW + k%3 - 1;
      if (gh >= 0 && gh < HH && gw >= 0 && gw < WW)
        v = (double)feat[((size_t)(b*CIN + c)*HH + gh)*WW + gw] * s_attn[c];
    }
    xw[p][r] = v;
  }
  __syncthreads();

  const int oc = tid & 63, cq = tid >> 6;
  double acc0 = 0.0, acc1 = 0.0, acc2 = 0.0, acc3 = 0.0;
  const float* wp = w9 + ((size_t)(cq*32)*OC + oc) * 12;
  for (int cc = 0; cc < 32; cc++) {
    const int c = cq*32 + cc;
    double wd[9];
    #pragma unroll
    for (int k = 0; k < 9; k++) wd[k] = (double)wp[k];
    wp += OC*12;
    const double* x0 = &xw[0][c*9];
    const double* x1 = &xw[1][c*9];
    const double* x2 = &xw[2][c*9];
    const double* x3 = &xw[3][c*9];
    #pragma unroll
    for (int k = 0; k < 9; k++) {
      acc0 = fma(wd[k], x0[k], acc0);
      acc1 = fma(wd[k], x1[k], acc1);
      acc2 = fma(wd[k], x2[k], acc2);
      acc3 = fma(wd[k], x3[k], acc3);
    }
  }
  part[cq][0][oc] = acc0;
  part[cq][1][oc] = acc1;
  part[cq][2][oc] = acc2;
  part[cq][3][oc] = acc3;
  __syncthreads();

  {
    const int p = tid >> 6, o = tid & 63;
    double z = part[0][p][o] + part[1][p][o] + part[2][p][o] + part[3][p][o]
             + (double)conv1_b[o];
    double g = 0.5 * z * (1.0 + erf(z * 0.70710678118654752440));
    double cv = g * (double)conv2_w[OC + o];
    #pragma unroll
    for (int m = 1; m <= 32; m <<= 1) cv += __shfl_xor(cv, m, 64);
    if (o == 0 && p < rem)
      lmap[(size_t)b*HW + s_pix[p]] = cv + (double)conv2_b[1];
  }
}

// ---------------- K7b: per-candidate score = sum_j exp64(lmap_j - m32) ----------------
__global__ __launch_bounds__(256) void score_kernel(const double* __restrict__ lmap,
                                                    const float* __restrict__ m32,
                                                    const int* __restrict__ cand_idx,
                                                    const int* __restrict__ cand_cnt,
                                                    double* __restrict__ cand_score) {
  const int b = blockIdx.y;
  const int slot = blockIdx.x * 256 + threadIdx.x;
  if (slot >= cand_cnt[b]) return;
  const int idx = cand_idx[b*CAP + slot];
  const int ph = idx / WW, pw = idx % WW;
  const double m = (double)m32[b];
  double s = 0.0;
  for (int dy = -1; dy <= 1; dy++) {
    int qh = ph + dy;
    if (qh < 0 || qh >= HH) continue;
    for (int dx = -1; dx <= 1; dx++) {
      int qw = pw + dx;
      if (qw < 0 || qw >= WW) continue;
      s += exp(lmap[(size_t)b*HW + qh*WW + qw] - m);
    }
  }
  cand_score[b*CAP + slot] = s;
}

// ---------------- K8: sort 2048 candidates (score desc, idx asc) + emit ----------------
__global__ __launch_bounds__(1024) void emit_kernel(const double* __restrict__ cand_score,
                                                    const int* __restrict__ cand_idx,
                                                    const int* __restrict__ cand_cnt,
                                                    const float* __restrict__ depth,
                                                    float* __restrict__ points) {
  const int b = blockIdx.x;
  const int tid = threadIdx.x;
  __shared__ double vals[CAP];
  __shared__ int    idxs[CAP];

  int cnt = cand_cnt[b];
  for (int i = tid; i < CAP; i += 1024) {
    if (i < cnt) { vals[i] = cand_score[b*CAP + i]; idxs[i] = cand_idx[b*CAP + i]; }
    else         { vals[i] = -1.0;                  idxs[i] = 0x7FFFFFFF; }
  }
  __syncthreads();

  for (unsigned k = 2; k <= CAP; k <<= 1) {
    for (unsigned j = k >> 1; j > 0; j >>= 1) {
      unsigned t = (unsigned)tid;           // one pair per thread (CAP/2 = 1024)
      unsigned i1 = ((t & ~(j - 1u)) << 1) | (t & (j - 1u));
      unsigned i2 = i1 | j;
      double v1 = vals[i1], v2 = vals[i2];
      int    a1 = idxs[i1], a2 = idxs[i2];
      bool oneAfterTwo = (v1 < v2) || (v1 == v2 && a1 > a2);
      bool descSeg = ((i1 & k) == 0);
      if (descSeg ? oneAfterTwo : !oneAfterTwo) {
        vals[i1] = v2; idxs[i1] = a2;
        vals[i2] = v1; idxs[i2] = a1;
      }
      __syncthreads();
    }
  }

  if (tid < KPTS) {
    int idx = idxs[tid];
    float d = depth[(size_t)b * HW + idx];
    float xi = (float)(idx % WW) / (float)WW;
    float yi = (float)(idx / WW) / (float)HH;
    float* pp = points + ((size_t)b * KPTS + tid) * 3;
    pp[0] = xi; pp[1] = yi; pp[2] = d;
  }
}

extern "C" void kernel_launch(void* const* d_in, const int* in_sizes, int n_in,
                              void* d_out, int out_size, void* d_ws, size_t ws_size,
                              hipStream_t stream) {
  const float* feat    = (const float*)d_in[0];
  const float* attn_w  = (const float*)d_in[1];
  const float* attn_b  = (const float*)d_in[2];
  const float* conv1_w = (const float*)d_in[3];
  const float* conv1_b = (const float*)d_in[4];
  const float* conv2_w = (const float*)d_in[5];
  const float* conv2_b = (const float*)d_in[6];

  float* out    = (float*)d_out;
  float* points = out;                          // 16*512*3
  float* depth  = out + 24576;                  // 16*36864
  float* conf_f = out + 24576 + BATCH*HW;       // 16*36864

  // ws layout: doubles, then floats, then bf16, then ints  (~9.3 MB)
  double* wsd        = (double*)d_ws;
  double* pool_d     = wsd;                                    // 2048
  double* attn_d     = wsd + 2048;                             // 2048
  double* cand_score = wsd + 4096;                             // 16*2048
  double* lmap       = cand_score + BATCH*CAP;                 // 16*36864
  float*  wsf        = (float*)(lmap + (size_t)BATCH*HW);
  float*  logit32    = wsf;                                    // 589824 (reused as probs)
  float*  attn_f     = logit32 + (size_t)BATCH*HW;             // 2048
  float*  m32        = attn_f + 2048;                          // 16
  float*  w9         = m32 + 16;                               // 128*64*12 = 98304 (16B aligned)
  unsigned short* wbf = (unsigned short*)(w9 + CIN*OC*12);     // 73728 bf16
  int*    cand_idx   = (int*)(wbf + OC*CIN*9);                 // 16*2048
  int*    cand_cnt   = cand_idx + BATCH*CAP;                   // 16
  int*    upix       = cand_cnt + 16;                          // 16*18432
  int*    upix_cnt   = upix + BATCH*UMAX;                      // 16

  pool_kernel<<<BATCH*CIN, 256, 0, stream>>>(feat, pool_d);
  attn_kernel<<<BATCH, CIN, 0, stream>>>(pool_d, attn_w, attn_b, attn_d, attn_f);
  wtrans_kernel<<<(OC*CIN*9 + 255)/256, 256, 0, stream>>>(conv1_w, wbf, w9);
  dim3 cgrid(WW/16, HH/16, BATCH);
  conv_kernel<<<cgrid, 256, 0, stream>>>(feat, attn_f, wbf, conv1_b, conv2_w, conv2_b,
                                         depth, logit32);
  softmax_kernel<<<BATCH, 1024, 0, stream>>>(logit32, m32);   // in-place probs
  box_kernel<<<(BATCH*HW + 255)/256, 256, 0, stream>>>(logit32, conf_f);
  cand_kernel<<<BATCH, 1024, 0, stream>>>(conf_f, cand_idx, cand_cnt, upix, upix_cnt);
  logit_kernel<<<BATCH*UPB4, 256, 0, stream>>>(feat, attn_d, w9, conv1_b,
                                               conv2_w, conv2_b, upix, upix_cnt, lmap);
  score_kernel<<<dim3(CAP/256, BATCH), 256, 0, stream>>>(lmap, m32, cand_idx, cand_cnt,
                                                         cand_score);
  emit_kernel<<<BATCH, 1024, 0, stream>>>(cand_score, cand_idx, cand_cnt, depth, points);
}